// Round 9
// baseline (223.809 us; speedup 1.0000x reference)
//
#include <hip/hip_runtime.h>
#include <stdint.h>
#include <math.h>

// pred_out [8,5,768,768] f32, target_mask [8,1,768,768] i32 (0..3), num_target_classes=4.
#define B_ 8
#define C_ 5
#define H_ 768
#define W_ 768
#define HW_ (H_*W_)
#define HWq (HW_/4)            // 147456 float4 per plane
#define NPIX (B_*HW_)          // 4,718,592
#define NQUAD (NPIX/4)         // 1,179,648
#define TB 8
#define INVAL 0xFFFFFFFFu
#define LN2F 0.69314718056f
#define BIASF 16.2f
#define TILE 64
#define TPR 12
#define TPC 12
#define NTILES (B_*TPR*TPC)    // 1152
#define NNODES (NTILES*256)    // 294912
#define SEAMS_PER_IMG (11*768) // 8448
#define NB_HALF (B_*SEAMS_PER_IMG)   // 67584
#define NB_TOT (2*NB_HALF)           // 135168
#define SEAMBLK (NB_TOT/256)         // 528
#define SBLK 2304                    // k_stats grid; NQUAD == 2*SBLK*256 exactly
#define NTH (SBLK*256)               // 589824

typedef unsigned long long ull;

// ---------------- compact node union-find (lock-free, agent scope, L2-resident) ------------
static __device__ __forceinline__ unsigned pload(const unsigned* P, unsigned i) {
  return __hip_atomic_load(&P[i], __ATOMIC_RELAXED, __HIP_MEMORY_SCOPE_AGENT);
}
static __device__ unsigned findRootG(unsigned* P, unsigned i) {
  unsigned p = pload(P, i);
  if (p == i) return i;
  unsigned gp = pload(P, p);
  while (p != gp) {
    __hip_atomic_store(&P[i], gp, __ATOMIC_RELAXED, __HIP_MEMORY_SCOPE_AGENT);  // path halving
    i = p; p = gp; gp = pload(P, p);
  }
  return p;
}
static __device__ bool uniteG(unsigned* P, unsigned a, unsigned b) {
  a = findRootG(P, a);
  b = findRootG(P, b);
  while (a != b) {
    if (a < b) { unsigned t = a; a = b; b = t; }
    unsigned old = atomicCAS(&P[a], a, b);
    if (old == a) return true;     // one real merge
    a = findRootG(P, old);
    b = findRootG(P, b);
  }
  return false;
}
// ---------------- LDS union-find with high-16-bit payload (workgroup scope) ----------------
static __device__ __forceinline__ unsigned ploadL(const unsigned* P, unsigned i) {
  return __hip_atomic_load(&P[i], __ATOMIC_RELAXED, __HIP_MEMORY_SCOPE_WORKGROUP);
}
static __device__ unsigned findRootL(const unsigned* P, unsigned i) {
  unsigned p = ploadL(P, i) & 0xFFFFu;
  while (p != i) { i = p; p = ploadL(P, i) & 0xFFFFu; }
  return i;
}
static __device__ void uniteL(unsigned* P, unsigned a, unsigned b) {
  a = findRootL(P, a);
  b = findRootL(P, b);
  while (a != b) {
    if (a < b) { unsigned t = a; a = b; b = t; }
    unsigned old = atomicCAS(&P[a], 0xFFFF0000u | a, 0xFFFF0000u | b);
    if (old == (0xFFFF0000u | a)) return;
    a = findRootL(P, old & 0xFFFFu);
    b = findRootL(P, b);
  }
}

// ---------------- k_stats: argmax + single-u64 packed histogram + packed cls ----------------
// 32-way replicated LDS histogram (copy = lane&31): ONE u64 atomic per pixel, branchless.
// word: [63:57] cnt | [56:38] sum pred*2^12 | [37:20] sum (logit+16.2)*2^6 | [16:0] sum mag*2^6
__global__ __launch_bounds__(256) void k_stats(
    const float4* __restrict__ pred4, const int4* __restrict__ tgt4,
    unsigned* __restrict__ cls4, double* __restrict__ sp)
{
  __shared__ ull h[32][41];   // 10,496 B
  for (int i = threadIdx.x; i < 32*41; i += 256) (&h[0][0])[i] = 0ull;
  __syncthreads();
  const int cp = threadIdx.x & 31;
  const int tid = blockIdx.x * 256 + threadIdx.x;

#define DOQUAD(P0, P1, P2, P3, P4, T4, PACKED)                                 \
  {                                                                            \
    PACKED = 0u;                                                               \
    _Pragma("unroll")                                                          \
    for (int j = 0; j < 4; ++j) {                                              \
      float v0 = ((const float*)&(P0))[j];                                     \
      float v1 = ((const float*)&(P1))[j];                                     \
      float v2 = ((const float*)&(P2))[j];                                     \
      float v3 = ((const float*)&(P3))[j];                                     \
      float v4 = ((const float*)&(P4))[j];                                     \
      int tt = ((const int*)&(T4))[j];                                         \
      float best = v0; int bc = 0;                                             \
      if (v1 > best) { best = v1; bc = 1; }                                    \
      if (v2 > best) { best = v2; bc = 2; }                                    \
      if (v3 > best) { best = v3; bc = 3; }                                    \
      if (v4 > best) { best = v4; bc = 4; }                                    \
      unsigned tu = (unsigned)tt; if (tu >= TB) tu = TB - 1;                   \
      float pc = fminf(fmaxf(best, 1e-7f), 1.0f - 1e-7f);                      \
      float l2p = __log2f(pc);                                                 \
      float l2m = __log2f(1.0f - pc);                                          \
      float logit = (l2p - l2m) * LN2F;                                        \
      float mag   = -l2m * LN2F;                                               \
      ull w = (1ull << 57)                                                     \
            | ((ull)__float2uint_rn(best * 4096.0f) << 38)                     \
            | ((ull)__float2uint_rn((logit + BIASF) * 64.0f) << 20)            \
            | (ull)__float2uint_rn(mag * 64.0f);                               \
      if (!bc) w = 1ull << 57;                                                 \
      atomicAdd(&h[cp][(int)tu * C_ + bc], w);                                 \
      PACKED |= ((unsigned)bc) << (8 * j);                                     \
    }                                                                          \
  }

  {
    int q0 = tid;
    int q1 = tid + NTH;                    // both always in range: NQUAD == 2*NTH
    int b0 = q0 / HWq, h0 = q0 - b0 * HWq;
    int b1 = q1 / HWq, h1 = q1 - b1 * HWq;
    const float4* ba = pred4 + (size_t)b0 * (C_*HWq) + h0;
    const float4* bb = pred4 + (size_t)b1 * (C_*HWq) + h1;
    float4 a0 = ba[0], a1 = ba[HWq], a2 = ba[2*HWq], a3 = ba[3*HWq], a4 = ba[4*HWq];
    float4 c0 = bb[0], c1 = bb[HWq], c2 = bb[2*HWq], c3 = bb[3*HWq], c4 = bb[4*HWq];
    int4 ta = tgt4[q0];
    int4 tb = tgt4[q1];
    unsigned pk0, pk1;
    DOQUAD(a0, a1, a2, a3, a4, ta, pk0)
    DOQUAD(c0, c1, c2, c3, c4, tb, pk1)
    cls4[q0] = pk0;
    cls4[q1] = pk1;
  }
#undef DOQUAD
  __syncthreads();
  if (threadIdx.x < 160) {
    int slot = threadIdx.x >> 2, comp = threadIdx.x & 3;
    double s = 0.0;
#pragma unroll
    for (int c = 0; c < 32; ++c) {
      ull w = h[c][slot];
      if (comp == 0)      s += (double)(w >> 57);
      else if (comp == 1) s += (double)((w >> 38) & 0x7FFFFull) * (1.0/4096.0);
      else if (comp == 2) s += (double)((w >> 20) & 0x3FFFFull) * (1.0/64.0);
      else                s += (double)(w & 0x1FFFFull) * (1.0/64.0);
    }
    sp[(size_t)blockIdx.x * 160 + threadIdx.x] = s;
  }
}

// ---------------- k_ccl: tile-local CCL, register-resident neighbor checks ----------------
__global__ __launch_bounds__(256) void k_ccl(
    const unsigned* __restrict__ cls4, unsigned short* __restrict__ border,
    unsigned* __restrict__ P2, unsigned* __restrict__ rootcnt,
    unsigned* __restrict__ smtot, unsigned* __restrict__ done)
{
  __shared__ unsigned lab[TILE*TILE];        // 16 KB (payload in high 16 bits)
  __shared__ unsigned lclsw[TILE*TILE/4];    // 4 KB
  __shared__ unsigned s_rt[4];
  unsigned char* lcls = (unsigned char*)lclsw;

  int blk = blockIdx.x;
  int b = blk / (TPR*TPC);
  int rem = blk - b * (TPR*TPC);
  int ty0 = (rem / TPR) * TILE;
  int tx0 = (rem - (rem / TPR) * TPR) * TILE;

  if (threadIdx.x < 4) s_rt[threadIdx.x] = 0u;
  if (blk == 0 && threadIdx.x < 5) {        // init fused-seam bookkeeping (ws is poisoned)
    if (threadIdx.x < 4) smtot[threadIdx.x] = 0u;
    else done[0] = 0u;
  }
  {
    unsigned n = (unsigned)blk * 256u + threadIdx.x;
    P2[n] = n;
  }
  const int r = threadIdx.x >> 2, cq = threadIdx.x & 3;
  const int seg = r * 64 + cq * 16;
  union { uint4 q; unsigned char bch[16]; unsigned w[4]; } A, D;
  {
    const uint4* src = (const uint4*)(cls4 + ((b * HW_ + (ty0 + r) * W_ + tx0) >> 2));
    A.q = src[cq];
    *(uint4*)&lclsw[r * 16 + cq * 4] = A.q;
  }
#pragma unroll
  for (int m = 0; m < 4; ++m) {
    uint4 lw;
    unsigned* lp = (unsigned*)&lw;
#pragma unroll
    for (int k = 0; k < 4; ++k) {
      int li = seg + m * 4 + k;
      unsigned c = (A.w[m] >> (8 * k)) & 255u;
      lp[k] = c ? (0xFFFF0000u | (unsigned)li) : INVAL;
    }
    *(uint4*)&lab[seg + m * 4] = lw;
  }
  __syncthreads();

  bool hasDown = (r < 63);
  if (hasDown) D.q = *(const uint4*)&lclsw[(r + 1) * 16 + cq * 4];
  else D.q = make_uint4(0, 0, 0, 0);
  unsigned rb = (cq < 3) ? (unsigned)lcls[seg + 16] : 0u;
#pragma unroll
  for (int j = 0; j < 16; ++j) {
    unsigned c = A.bch[j];
    if (!c) continue;
    int li = seg + j;
    unsigned cr = (j < 15) ? (unsigned)A.bch[j + 1] : rb;
    if (cr == c) uniteL(lab, li, li + 1);
    if (D.bch[j] == c) uniteL(lab, li, li + 64);
  }
  __syncthreads();

#pragma unroll
  for (int m = 0; m < 4; ++m) {
    uint4 lw = *(const uint4*)&lab[seg + m * 4];
    const unsigned* lp = (const unsigned*)&lw;
#pragma unroll
    for (int k = 0; k < 4; ++k) {
      int li = seg + m * 4 + k;
      unsigned c = A.bch[m * 4 + k];
      if (c && (lp[k] & 0xFFFFu) == (unsigned)li) atomicAdd(&s_rt[c - 1], 1u);
    }
  }
  int bp = threadIdx.x;
  int tx, ty;
  if (bp < 64)       { ty = 0;  tx = bp; }
  else if (bp < 128) { ty = 63; tx = bp - 64; }
  else if (bp < 192) { tx = 0;  ty = bp - 128; }
  else               { tx = 63; ty = bp - 192; }
  int li = ty * 64 + tx;
  unsigned char c = lcls[li];
  unsigned rt = 0;
  if (c) {
    rt = findRootL(lab, (unsigned)li);
    atomicMin(&lab[rt], ((unsigned)bp << 16) | rt);
  }
  __syncthreads();
  unsigned sub = c ? (lab[rt] >> 16) : 0u;
  border[blk * 256 + bp] = (unsigned short)(((unsigned)c << 8) | sub);
  if (threadIdx.x < 4) rootcnt[blk * 4 + threadIdx.x] = s_rt[threadIdx.x];
}

// ---------------- k_seam: node-graph merge + sp reduction + fused final (last block) -------
#define SH_CNT(t,c)   shist[((t)*C_+(c))*4 + 0]
#define SH_PRED(t,c)  shist[((t)*C_+(c))*4 + 1]
#define SH_LRAW(t,c)  shist[((t)*C_+(c))*4 + 2]
#define SH_MAG(t,c)   shist[((t)*C_+(c))*4 + 3]
__global__ __launch_bounds__(256) void k_seam(
    const unsigned short* __restrict__ border, unsigned* __restrict__ P2,
    unsigned* __restrict__ smtot, unsigned* __restrict__ done,
    const double* __restrict__ sp, double* __restrict__ spf,
    const unsigned* __restrict__ rootcnt, const int* __restrict__ ntcp,
    float* __restrict__ out)
{
  __shared__ unsigned s_sub[4];
  __shared__ double red[256];
  __shared__ int s_last;
  if (threadIdx.x < 4) s_sub[threadIdx.x] = 0u;
  __syncthreads();
  int idx = blockIdx.x * blockDim.x + threadIdx.x;
  if (idx < NB_TOT) {
    int tA, tB, pA, pB;
    if (idx < NB_HALF) {             // down seams
      int b = idx / SEAMS_PER_IMG;
      int r = idx - b * SEAMS_PER_IMG;
      int seam = r / W_;
      int x = r - seam * W_;
      int tj = x >> 6, k = x & 63;
      tA = (b * TPC + seam) * TPR + tj;
      tB = tA + TPR;
      pA = tA * 256 + 64 + k;
      pB = tB * 256 + 0 + k;
    } else {                         // right seams
      int i2 = idx - NB_HALF;
      int b = i2 / SEAMS_PER_IMG;
      int r = i2 - b * SEAMS_PER_IMG;
      int seam = r / H_;
      int y = r - seam * H_;
      int ti = y >> 6, k = y & 63;
      tA = (b * TPC + ti) * TPR + seam;
      tB = tA + 1;
      pA = tA * 256 + 192 + k;
      pB = tB * 256 + 128 + k;
    }
    unsigned a16 = border[pA];
    unsigned b16 = border[pB];
    unsigned ca = a16 >> 8, cb = b16 >> 8;
    if (ca && ca == cb) {
      if (uniteG(P2, (unsigned)tA * 256u + (a16 & 255u),
                     (unsigned)tB * 256u + (b16 & 255u)))
        atomicAdd(&s_sub[ca - 1], 1u);
    }
  }
  __syncthreads();
  // fold: blocks 0..159 reduce one histogram slot-comp over all SBLK partials
  if (blockIdx.x < 160) {
    double s = 0.0;
    for (int j = threadIdx.x; j < SBLK; j += 256) s += sp[(size_t)j * 160 + blockIdx.x];
    red[threadIdx.x] = s;
    __syncthreads();
    for (int off = 128; off; off >>= 1) {
      if (threadIdx.x < off) red[threadIdx.x] += red[threadIdx.x + off];
      __syncthreads();
    }
  }
  // tid0 publishes ALL of this block's global side effects, then takes a ticket (release).
  if (threadIdx.x == 0) {
    if (blockIdx.x < 160)
      __hip_atomic_store(&spf[blockIdx.x], red[0], __ATOMIC_RELAXED, __HIP_MEMORY_SCOPE_AGENT);
#pragma unroll
    for (int c2 = 0; c2 < 4; ++c2)
      if (s_sub[c2]) atomicAdd(&smtot[c2], s_sub[c2]);
    unsigned tk = __hip_atomic_fetch_add(&done[0], 1u, __ATOMIC_ACQ_REL,
                                         __HIP_MEMORY_SCOPE_AGENT);
    s_last = (tk == SEAMBLK - 1);
  }
  __syncthreads();
  if (!s_last) return;

  // ---------------- fused final phase (one block, 256 threads, scratch-free) ----------------
  __shared__ double shist[160];
  __shared__ double s_col[C_][3];       // per-class colsums: 0=cnt, 1=pred, 2=log1m (signed)
  __shared__ unsigned s_cnti[TB*C_];
  __shared__ unsigned s_ctot[C_];
  __shared__ unsigned s_nc[4], s_sm[4];
  __shared__ float s_ph[C_];
  __shared__ double s_term[TB];
  __shared__ int s_NT;
  __shared__ int s_nun;

  if (threadIdx.x < 4) {
    s_nc[threadIdx.x] = 0u;
    s_sm[threadIdx.x] = __hip_atomic_load(&smtot[threadIdx.x], __ATOMIC_RELAXED,
                                          __HIP_MEMORY_SCOPE_AGENT);
  }
  if (threadIdx.x < TB) s_term[threadIdx.x] = 0.0;
  __syncthreads();
  if (threadIdx.x < 160)
    shist[threadIdx.x] = __hip_atomic_load(&spf[threadIdx.x], __ATOMIC_RELAXED,
                                           __HIP_MEMORY_SCOPE_AGENT);
  {
    unsigned a = 0;
    for (int j = threadIdx.x; j < NTILES * 4; j += 256) a += rootcnt[j];  // j&3 fixed/thread
    if (a) atomicAdd(&s_nc[threadIdx.x & 3], a);
  }
  if (threadIdx.x == 0) {
    int NT = ntcp[0];
    if (NT < 1) NT = 1;
    if (NT > TB) NT = TB;
    s_NT = NT;
  }
  __syncthreads();

  if (threadIdx.x < TB * C_) s_cnti[threadIdx.x] = (unsigned)llrint(shist[threadIdx.x * 4]);
  __syncthreads();

  if (threadIdx.x < C_) {
    int c = threadIdx.x;
    double sc = 0.0, sp2 = 0.0, sl = 0.0;
    unsigned ct = 0;
#pragma unroll
    for (int t = 0; t < TB; ++t) {
      sc += SH_CNT(t, c);
      sp2 += SH_PRED(t, c);
      sl += -SH_MAG(t, c);
      ct += s_cnti[t * C_ + c];
    }
    s_col[c][0] = sc; s_col[c][1] = sp2; s_col[c][2] = sl;
    s_ctot[c] = ct;
  }
  __syncthreads();

  // ph_tab: exact f32 replay incl. int32 wrap of n_comp*last_i (thread 0, registers only)
  if (threadIdx.x == 0) {
#pragma unroll
    for (int cc = 0; cc < C_; ++cc) {
      float ph = 0.0f;
      int li2 = 1;
#pragma unroll
      for (int v = 1; v < C_; ++v) {
        unsigned ncv = s_nc[v - 1] - s_sm[v - 1];
        if (s_ctot[v] > 0) {
          int prod = (int)(ncv * (unsigned)li2);
          float sv = (float)prod;
          float inc = ((cc == v) ? 1.0f : 0.0f) + sv;
          ph = ph + inc;
          li2 = li2 + (int)ncv + ((s_ctot[v] < (unsigned)NPIX) ? 1 : 0);
        }
      }
      s_ph[cc] = ph;
    }
  }
  __syncthreads();

  const float EPSF = 1e-7f;
  const double L1 = (double)logf(1.0f - EPSF);
  const double M1 = (double)log1pf(-(1.0f - EPSF));
  const double L0 = (double)logf(EPSF);
  const double M0 = (double)log1pf(-EPSF);
  const double N = (double)NPIX;
  const double BIASD = (double)BIASF;
  const int NT = s_NT;

  if (threadIdx.x == 0) {
    double nt0 = 0;
#pragma unroll
    for (int c = 0; c < C_; ++c) nt0 += SH_CNT(0, c);
    double np1 = (double)s_ctot[0];
    double n11 = SH_CNT(0, 0);
    s_term[0] = -(n11*L1 + (nt0 - n11)*L0 + (np1 - n11)*M1 + (N - nt0 - np1 + n11)*M0) / N
                + 1.0 - (2.0*n11 + 1.0) / (np1 + nt0 + 1.0);
    int nun = 0;
    for (int t = 0; t < NT; ++t) {
      long long s = 0;
#pragma unroll
      for (int c = 0; c < C_; ++c) s += (long long)s_cnti[t * C_ + c];
      if (s) nun++;
    }
    s_nun = nun;
  } else if (threadIdx.x < (unsigned)NT) {
    int t = threadIdx.x;
    long long ntti = 0;
#pragma unroll
    for (int c = 0; c < C_; ++c) ntti += (long long)s_cnti[t * C_ + c];
    if (ntti != 0) {
      double ntt = 0;
#pragma unroll
      for (int c = 0; c < C_; ++c) ntt += SH_CNT(t, c);
      float pht[C_] = {s_ph[0], s_ph[1], s_ph[2], s_ph[3], s_ph[4]};
      int idx2[C_] = {0, 1, 2, 3, 4};
#pragma unroll
      for (int i = 1; i < C_; ++i)
        for (int j = i; j > 0 && pht[idx2[j]] < pht[idx2[j-1]]; --j) {
          int tmp = idx2[j]; idx2[j] = idx2[j-1]; idx2[j-1] = tmp;
        }
      long long k = (ntti - 1) / 2;
      float med = pht[idx2[C_ - 1]];
      long long cum = 0;
#pragma unroll
      for (int i = 0; i < C_; ++i) {
        cum += (long long)s_cnti[t * C_ + idx2[i]];
        if (cum > k) { med = pht[idx2[i]]; break; }
      }
      double A = 0, Bt = 0, inter = 0, sum_p = 0, ex = 0, nfg_t = 0, nfg_all = 0;
#pragma unroll
      for (int c = 1; c < C_; ++c) {
        double cnt_tc = SH_CNT(t, c);
        double mag_tc = SH_MAG(t, c);
        double spred_tc = SH_PRED(t, c);
        if (pht[c] == med) {
          double logit = SH_LRAW(t, c) - BIASD * cnt_tc;
          A += logit - mag_tc;                 // logpc = logit + log1m
          inter += spred_tc;
          nfg_t += cnt_tc;
          nfg_all += s_col[c][0];
          sum_p += s_col[c][1];
          Bt += s_col[c][2] - (-mag_tc);       // sum over t2 != t of log1m
        } else {
          ex += spred_tc;
        }
      }
      double bce  = -(A + Bt + (ntt - nfg_t)*L0 + (N - ntt - (nfg_all - nfg_t))*M0) / N;
      double dice = 1.0 - (2.0*inter + 1.0) / (sum_p + ntt + 1.0);
      s_term[t] = bce + dice + ex / ntt;
    }
  }
  __syncthreads();
  if (threadIdx.x == 0) {
    double res = 0.0;
#pragma unroll
    for (int t = 0; t < TB; ++t) res += s_term[t];
    out[0] = (float)(res / (double)(2 * s_nun + 1));
  }
}

extern "C" void kernel_launch(void* const* d_in, const int* in_sizes, int n_in,
                              void* d_out, int out_size, void* d_ws, size_t ws_size,
                              hipStream_t stream) {
  const float* pred = (const float*)d_in[0];
  const int* tgt = (const int*)d_in[1];
  const int* ntc = (const int*)d_in[2];
  float* out = (float*)d_out;
  char* ws = (char*)d_ws;
  // ws layout (16B-aligned chunks): cls4 | sp | spf | P2 | border | rootcnt | smtot | done
  size_t off = 0;
  unsigned* cls4 = (unsigned*)(ws + off);        off += (size_t)NQUAD * 4;          // 4,718,592
  double* sp = (double*)(ws + off);              off += (size_t)SBLK * 160 * 8;     // 2,949,120
  double* spf = (double*)(ws + off);             off += 160 * 8;                    // 1,280
  unsigned* P2 = (unsigned*)(ws + off);          off += (size_t)NNODES * 4;         // 1,179,648
  unsigned short* border = (unsigned short*)(ws + off); off += (size_t)NTILES * 256 * 2; // 589,824
  unsigned* rootcnt = (unsigned*)(ws + off);     off += (size_t)NTILES * 4 * 4;     // 18,432
  unsigned* smtot = (unsigned*)(ws + off);       off += 16;
  unsigned* done = (unsigned*)(ws + off);        off += 16;

  hipLaunchKernelGGL(k_stats, dim3(SBLK), dim3(256), 0, stream,
                     (const float4*)pred, (const int4*)tgt, cls4, sp);
  hipLaunchKernelGGL(k_ccl, dim3(NTILES), dim3(256), 0, stream,
                     cls4, border, P2, rootcnt, smtot, done);
  hipLaunchKernelGGL(k_seam, dim3(SEAMBLK), dim3(256), 0, stream,
                     border, P2, smtot, done, sp, spf, rootcnt, ntc, out);
}

// Round 10
// 199.115 us; speedup vs baseline: 1.1240x; 1.1240x over previous
//
#include <hip/hip_runtime.h>
#include <stdint.h>
#include <math.h>

// pred_out [8,5,768,768] f32, target_mask [8,1,768,768] i32 (0..3), num_target_classes=4.
#define B_ 8
#define C_ 5
#define H_ 768
#define W_ 768
#define HW_ (H_*W_)
#define HWq (HW_/4)            // 147456 float4 per plane
#define NPIX (B_*HW_)          // 4,718,592
#define NQUAD (NPIX/4)         // 1,179,648
#define TB 8
#define INVAL 0xFFFFFFFFu
#define LN2F 0.69314718056f
#define BIASF 16.2f
#define TILE 64
#define TPR 12
#define TPC 12
#define NTILES (B_*TPR*TPC)    // 1152
#define NNODES (NTILES*256)    // 294912
#define SEAMS_PER_IMG (11*768) // 8448
#define NB_HALF (B_*SEAMS_PER_IMG)   // 67584
#define NB_TOT (2*NB_HALF)           // 135168
#define SEAMBLK (NB_TOT/256)         // 528
#define SBLK 2304                    // k_stats grid; NQUAD == 2*SBLK*256 exactly
#define NTH (SBLK*256)               // 589824

typedef unsigned long long ull;

// ---------------- compact node union-find (lock-free, agent scope, L2-resident) ------------
static __device__ __forceinline__ unsigned pload(const unsigned* P, unsigned i) {
  return __hip_atomic_load(&P[i], __ATOMIC_RELAXED, __HIP_MEMORY_SCOPE_AGENT);
}
static __device__ unsigned findRootG(unsigned* P, unsigned i) {
  unsigned p = pload(P, i);
  if (p == i) return i;
  unsigned gp = pload(P, p);
  while (p != gp) {
    __hip_atomic_store(&P[i], gp, __ATOMIC_RELAXED, __HIP_MEMORY_SCOPE_AGENT);  // path halving
    i = p; p = gp; gp = pload(P, p);
  }
  return p;
}
static __device__ bool uniteG(unsigned* P, unsigned a, unsigned b) {
  a = findRootG(P, a);
  b = findRootG(P, b);
  while (a != b) {
    if (a < b) { unsigned t = a; a = b; b = t; }
    unsigned old = atomicCAS(&P[a], a, b);
    if (old == a) return true;     // one real merge
    a = findRootG(P, old);
    b = findRootG(P, b);
  }
  return false;
}
// ---------------- LDS union-find with high-16-bit payload (workgroup scope) ----------------
static __device__ __forceinline__ unsigned ploadL(const unsigned* P, unsigned i) {
  return __hip_atomic_load(&P[i], __ATOMIC_RELAXED, __HIP_MEMORY_SCOPE_WORKGROUP);
}
static __device__ unsigned findRootL(const unsigned* P, unsigned i) {
  unsigned p = ploadL(P, i) & 0xFFFFu;
  while (p != i) { i = p; p = ploadL(P, i) & 0xFFFFu; }
  return i;
}
static __device__ void uniteL(unsigned* P, unsigned a, unsigned b) {
  a = findRootL(P, a);
  b = findRootL(P, b);
  while (a != b) {
    if (a < b) { unsigned t = a; a = b; b = t; }
    unsigned old = atomicCAS(&P[a], 0xFFFF0000u | a, 0xFFFF0000u | b);
    if (old == (0xFFFF0000u | a)) return;
    a = findRootL(P, old & 0xFFFFu);
    b = findRootL(P, b);
  }
}

// ---------------- k_stats: argmax + single-u64 packed histogram + packed cls ----------------
// 32-way replicated LDS histogram (copy = lane&31): ONE u64 atomic per pixel.
// word: [63:57] cnt | [56:38] sum pred*2^12 | [37:20] sum (logit+16.2)*2^6 | [16:0] sum mag*2^6
__global__ __launch_bounds__(256) void k_stats(
    const float4* __restrict__ pred4, const int4* __restrict__ tgt4,
    unsigned* __restrict__ cls4, double* __restrict__ sp)
{
  __shared__ ull h[32][41];   // 10,496 B
  for (int i = threadIdx.x; i < 32*41; i += 256) (&h[0][0])[i] = 0ull;
  __syncthreads();
  const int cp = threadIdx.x & 31;
  const int tid = blockIdx.x * 256 + threadIdx.x;

#define DOQUAD(P0, P1, P2, P3, P4, T4, PACKED)                                 \
  {                                                                            \
    PACKED = 0u;                                                               \
    _Pragma("unroll")                                                          \
    for (int j = 0; j < 4; ++j) {                                              \
      float v0 = ((const float*)&(P0))[j];                                     \
      float v1 = ((const float*)&(P1))[j];                                     \
      float v2 = ((const float*)&(P2))[j];                                     \
      float v3 = ((const float*)&(P3))[j];                                     \
      float v4 = ((const float*)&(P4))[j];                                     \
      int tt = ((const int*)&(T4))[j];                                         \
      float best = v0; int bc = 0;                                             \
      if (v1 > best) { best = v1; bc = 1; }                                    \
      if (v2 > best) { best = v2; bc = 2; }                                    \
      if (v3 > best) { best = v3; bc = 3; }                                    \
      if (v4 > best) { best = v4; bc = 4; }                                    \
      unsigned tu = (unsigned)tt; if (tu >= TB) tu = TB - 1;                   \
      ull w;                                                                   \
      if (bc) {                                                                \
        float pc = fminf(fmaxf(best, 1e-7f), 1.0f - 1e-7f);                    \
        float l2p = __log2f(pc);                                               \
        float l2m = __log2f(1.0f - pc);                                        \
        float logit = (l2p - l2m) * LN2F;                                      \
        float mag   = -l2m * LN2F;                                             \
        w = (1ull << 57)                                                       \
          | ((ull)__float2uint_rn(best * 4096.0f) << 38)                       \
          | ((ull)__float2uint_rn((logit + BIASF) * 64.0f) << 20)              \
          | (ull)__float2uint_rn(mag * 64.0f);                                 \
      } else {                                                                 \
        w = 1ull << 57;                                                        \
      }                                                                        \
      atomicAdd(&h[cp][(int)tu * C_ + bc], w);                                 \
      PACKED |= ((unsigned)bc) << (8 * j);                                     \
    }                                                                          \
  }

  {
    int q0 = tid;
    int q1 = tid + NTH;                    // both always in range: NQUAD == 2*NTH
    int b0 = q0 / HWq, h0 = q0 - b0 * HWq;
    int b1 = q1 / HWq, h1 = q1 - b1 * HWq;
    const float4* ba = pred4 + (size_t)b0 * (C_*HWq) + h0;
    const float4* bb = pred4 + (size_t)b1 * (C_*HWq) + h1;
    float4 a0 = ba[0], a1 = ba[HWq], a2 = ba[2*HWq], a3 = ba[3*HWq], a4 = ba[4*HWq];
    float4 c0 = bb[0], c1 = bb[HWq], c2 = bb[2*HWq], c3 = bb[3*HWq], c4 = bb[4*HWq];
    int4 ta = tgt4[q0];
    int4 tb = tgt4[q1];
    unsigned pk0, pk1;
    DOQUAD(a0, a1, a2, a3, a4, ta, pk0)
    DOQUAD(c0, c1, c2, c3, c4, tb, pk1)
    cls4[q0] = pk0;
    cls4[q1] = pk1;
  }
#undef DOQUAD
  __syncthreads();
  if (threadIdx.x < 160) {
    int slot = threadIdx.x >> 2, comp = threadIdx.x & 3;
    double s = 0.0;
#pragma unroll
    for (int c = 0; c < 32; ++c) {
      ull w = h[c][slot];
      if (comp == 0)      s += (double)(w >> 57);
      else if (comp == 1) s += (double)((w >> 38) & 0x7FFFFull) * (1.0/4096.0);
      else if (comp == 2) s += (double)((w >> 20) & 0x3FFFFull) * (1.0/64.0);
      else                s += (double)(w & 0x1FFFFull) * (1.0/64.0);
    }
    sp[(size_t)blockIdx.x * 160 + threadIdx.x] = s;
  }
}

// ---------------- k_ccl: tile-local CCL, register-resident neighbor checks ----------------
__global__ __launch_bounds__(256) void k_ccl(
    const unsigned* __restrict__ cls4, unsigned short* __restrict__ border,
    unsigned* __restrict__ P2, unsigned* __restrict__ rootcnt)
{
  __shared__ unsigned lab[TILE*TILE];        // 16 KB (payload in high 16 bits)
  __shared__ unsigned lclsw[TILE*TILE/4];    // 4 KB
  __shared__ unsigned s_rt[4];
  unsigned char* lcls = (unsigned char*)lclsw;

  int blk = blockIdx.x;
  int b = blk / (TPR*TPC);
  int rem = blk - b * (TPR*TPC);
  int ty0 = (rem / TPR) * TILE;
  int tx0 = (rem - (rem / TPR) * TPR) * TILE;

  if (threadIdx.x < 4) s_rt[threadIdx.x] = 0u;
  {
    unsigned n = (unsigned)blk * 256u + threadIdx.x;
    P2[n] = n;
  }
  const int r = threadIdx.x >> 2, cq = threadIdx.x & 3;
  const int seg = r * 64 + cq * 16;
  union { uint4 q; unsigned char bch[16]; unsigned w[4]; } A, D;
  {
    const uint4* src = (const uint4*)(cls4 + ((b * HW_ + (ty0 + r) * W_ + tx0) >> 2));
    A.q = src[cq];
    *(uint4*)&lclsw[r * 16 + cq * 4] = A.q;
  }
#pragma unroll
  for (int m = 0; m < 4; ++m) {
    uint4 lw;
    unsigned* lp = (unsigned*)&lw;
#pragma unroll
    for (int k = 0; k < 4; ++k) {
      int li = seg + m * 4 + k;
      unsigned c = (A.w[m] >> (8 * k)) & 255u;
      lp[k] = c ? (0xFFFF0000u | (unsigned)li) : INVAL;
    }
    *(uint4*)&lab[seg + m * 4] = lw;
  }
  __syncthreads();

  bool hasDown = (r < 63);
  if (hasDown) D.q = *(const uint4*)&lclsw[(r + 1) * 16 + cq * 4];
  else D.q = make_uint4(0, 0, 0, 0);
  unsigned rb = (cq < 3) ? (unsigned)lcls[seg + 16] : 0u;
#pragma unroll
  for (int j = 0; j < 16; ++j) {
    unsigned c = A.bch[j];
    if (!c) continue;
    int li = seg + j;
    unsigned cr = (j < 15) ? (unsigned)A.bch[j + 1] : rb;
    if (cr == c) uniteL(lab, li, li + 1);
    if (D.bch[j] == c) uniteL(lab, li, li + 64);
  }
  __syncthreads();

#pragma unroll
  for (int m = 0; m < 4; ++m) {
    uint4 lw = *(const uint4*)&lab[seg + m * 4];
    const unsigned* lp = (const unsigned*)&lw;
#pragma unroll
    for (int k = 0; k < 4; ++k) {
      int li = seg + m * 4 + k;
      unsigned c = A.bch[m * 4 + k];
      if (c && (lp[k] & 0xFFFFu) == (unsigned)li) atomicAdd(&s_rt[c - 1], 1u);
    }
  }
  int bp = threadIdx.x;
  int tx, ty;
  if (bp < 64)       { ty = 0;  tx = bp; }
  else if (bp < 128) { ty = 63; tx = bp - 64; }
  else if (bp < 192) { tx = 0;  ty = bp - 128; }
  else               { tx = 63; ty = bp - 192; }
  int li = ty * 64 + tx;
  unsigned char c = lcls[li];
  unsigned rt = 0;
  if (c) {
    rt = findRootL(lab, (unsigned)li);
    atomicMin(&lab[rt], ((unsigned)bp << 16) | rt);
  }
  __syncthreads();
  unsigned sub = c ? (lab[rt] >> 16) : 0u;
  border[blk * 256 + bp] = (unsigned short)(((unsigned)c << 8) | sub);
  if (threadIdx.x < 4) rootcnt[blk * 4 + threadIdx.x] = s_rt[threadIdx.x];
}

// ---------------- k_seam: node-graph merge + sp reduction in idle blocks ----------------
__global__ __launch_bounds__(256) void k_seam(const unsigned short* __restrict__ border,
                                              unsigned* __restrict__ P2,
                                              unsigned* __restrict__ smcnt,
                                              const double* __restrict__ sp,
                                              double* __restrict__ spf)
{
  __shared__ unsigned s_sub[4];
  __shared__ double red[256];
  if (threadIdx.x < 4) s_sub[threadIdx.x] = 0u;
  __syncthreads();
  int idx = blockIdx.x * blockDim.x + threadIdx.x;
  if (idx < NB_TOT) {
    int tA, tB, pA, pB;
    if (idx < NB_HALF) {             // down seams
      int b = idx / SEAMS_PER_IMG;
      int r = idx - b * SEAMS_PER_IMG;
      int seam = r / W_;
      int x = r - seam * W_;
      int tj = x >> 6, k = x & 63;
      tA = (b * TPC + seam) * TPR + tj;
      tB = tA + TPR;
      pA = tA * 256 + 64 + k;
      pB = tB * 256 + 0 + k;
    } else {                         // right seams
      int i2 = idx - NB_HALF;
      int b = i2 / SEAMS_PER_IMG;
      int r = i2 - b * SEAMS_PER_IMG;
      int seam = r / H_;
      int y = r - seam * H_;
      int ti = y >> 6, k = y & 63;
      tA = (b * TPC + ti) * TPR + seam;
      tB = tA + 1;
      pA = tA * 256 + 192 + k;
      pB = tB * 256 + 128 + k;
    }
    unsigned a16 = border[pA];
    unsigned b16 = border[pB];
    unsigned ca = a16 >> 8, cb = b16 >> 8;
    if (ca && ca == cb) {
      if (uniteG(P2, (unsigned)tA * 256u + (a16 & 255u),
                     (unsigned)tB * 256u + (b16 & 255u)))
        atomicAdd(&s_sub[ca - 1], 1u);
    }
  }
  __syncthreads();
  if (threadIdx.x < 4) smcnt[blockIdx.x * 4 + threadIdx.x] = s_sub[threadIdx.x];
  if (blockIdx.x < 160) {
    double s = 0.0;
    for (int j = threadIdx.x; j < SBLK; j += 256) s += sp[(size_t)j * 160 + blockIdx.x];
    red[threadIdx.x] = s;
    __syncthreads();
    for (int off = 128; off; off >>= 1) {
      if (threadIdx.x < off) red[threadIdx.x] += red[threadIdx.x + off];
      __syncthreads();
    }
    if (threadIdx.x == 0) spf[blockIdx.x] = red[0];
  }
}

// ---------------- k_final: scratch-free, parallel decode + per-t terms ----------------
// All state lives in LDS; per-target-class terms computed by separate threads.
#define SH_CNT(t,c)   shist[((t)*C_+(c))*4 + 0]
#define SH_PRED(t,c)  shist[((t)*C_+(c))*4 + 1]
#define SH_LRAW(t,c)  shist[((t)*C_+(c))*4 + 2]
#define SH_MAG(t,c)   shist[((t)*C_+(c))*4 + 3]
__global__ __launch_bounds__(256) void k_final(
    const double* __restrict__ spf, const unsigned* __restrict__ rootcnt,
    const unsigned* __restrict__ smcnt, const int* __restrict__ ntcp,
    float* __restrict__ out)
{
  __shared__ double shist[160];
  __shared__ double s_col[C_][3];       // per-class colsums: 0=cnt, 1=pred, 2=log1m (signed)
  __shared__ unsigned s_cnti[TB*C_];
  __shared__ unsigned s_ctot[C_];
  __shared__ unsigned s_nc[4], s_sm[4];
  __shared__ float s_ph[C_];
  __shared__ double s_term[TB];
  __shared__ int s_NT;
  __shared__ int s_nun;

  if (threadIdx.x < 4) { s_nc[threadIdx.x] = 0u; s_sm[threadIdx.x] = 0u; }
  if (threadIdx.x < TB) s_term[threadIdx.x] = 0.0;
  __syncthreads();
  if (threadIdx.x < 160) shist[threadIdx.x] = spf[threadIdx.x];
  {
    unsigned a = 0;
    for (int j = threadIdx.x; j < NTILES * 4; j += 256) a += rootcnt[j];  // j&3 fixed/thread
    if (a) atomicAdd(&s_nc[threadIdx.x & 3], a);
  }
  {
    unsigned a = 0;
    for (int j = threadIdx.x; j < SEAMBLK * 4; j += 256) a += smcnt[j];
    if (a) atomicAdd(&s_sm[threadIdx.x & 3], a);
  }
  if (threadIdx.x == 0) {
    int NT = ntcp[0];
    if (NT < 1) NT = 1;
    if (NT > TB) NT = TB;
    s_NT = NT;
  }
  __syncthreads();

  if (threadIdx.x < TB * C_) s_cnti[threadIdx.x] = (unsigned)llrint(shist[threadIdx.x * 4]);
  __syncthreads();

  if (threadIdx.x < C_) {
    int c = threadIdx.x;
    double sc = 0.0, sp2 = 0.0, sl = 0.0;
    unsigned ct = 0;
#pragma unroll
    for (int t = 0; t < TB; ++t) {
      sc += SH_CNT(t, c);
      sp2 += SH_PRED(t, c);
      sl += -SH_MAG(t, c);
      ct += s_cnti[t * C_ + c];
    }
    s_col[c][0] = sc; s_col[c][1] = sp2; s_col[c][2] = sl;
    s_ctot[c] = ct;
  }
  __syncthreads();

  // ph_tab: exact f32 replay incl. int32 wrap of n_comp*last_i (thread 0, registers only)
  if (threadIdx.x == 0) {
#pragma unroll
    for (int cc = 0; cc < C_; ++cc) {
      float ph = 0.0f;
      int li = 1;
#pragma unroll
      for (int v = 1; v < C_; ++v) {
        unsigned ncv = s_nc[v - 1] - s_sm[v - 1];
        if (s_ctot[v] > 0) {
          int prod = (int)(ncv * (unsigned)li);
          float sv = (float)prod;
          float inc = ((cc == v) ? 1.0f : 0.0f) + sv;
          ph = ph + inc;
          li = li + (int)ncv + ((s_ctot[v] < (unsigned)NPIX) ? 1 : 0);
        }
      }
      s_ph[cc] = ph;
    }
  }
  __syncthreads();

  const float EPSF = 1e-7f;
  const double L1 = (double)logf(1.0f - EPSF);
  const double M1 = (double)log1pf(-(1.0f - EPSF));
  const double L0 = (double)logf(EPSF);
  const double M0 = (double)log1pf(-EPSF);
  const double N = (double)NPIX;
  const double BIASD = (double)BIASF;
  const int NT = s_NT;

  if (threadIdx.x == 0) {
    // term 0 + nun
    double nt0 = 0;
#pragma unroll
    for (int c = 0; c < C_; ++c) nt0 += SH_CNT(0, c);
    double np1 = (double)s_ctot[0];
    double n11 = SH_CNT(0, 0);
    s_term[0] = -(n11*L1 + (nt0 - n11)*L0 + (np1 - n11)*M1 + (N - nt0 - np1 + n11)*M0) / N
                + 1.0 - (2.0*n11 + 1.0) / (np1 + nt0 + 1.0);
    int nun = 0;
    for (int t = 0; t < NT; ++t) {
      long long s = 0;
#pragma unroll
      for (int c = 0; c < C_; ++c) s += (long long)s_cnti[t * C_ + c];
      if (s) nun++;
    }
    s_nun = nun;
  } else if (threadIdx.x < (unsigned)NT) {
    int t = threadIdx.x;
    long long ntti = 0;
#pragma unroll
    for (int c = 0; c < C_; ++c) ntti += (long long)s_cnti[t * C_ + c];
    if (ntti != 0) {
      double ntt = 0;
#pragma unroll
      for (int c = 0; c < C_; ++c) ntt += SH_CNT(t, c);
      // median of ph over target-t pixels: sort 5 classes by ph
      float ph0 = s_ph[0], ph1 = s_ph[1], ph2 = s_ph[2], ph3 = s_ph[3], ph4 = s_ph[4];
      float pht[C_] = {ph0, ph1, ph2, ph3, ph4};
      int idx[C_] = {0, 1, 2, 3, 4};
#pragma unroll
      for (int i = 1; i < C_; ++i)
        for (int j = i; j > 0 && pht[idx[j]] < pht[idx[j-1]]; --j) {
          int tmp = idx[j]; idx[j] = idx[j-1]; idx[j-1] = tmp;
        }
      long long k = (ntti - 1) / 2;
      float med = pht[idx[C_ - 1]];
      long long cum = 0;
#pragma unroll
      for (int i = 0; i < C_; ++i) {
        cum += (long long)s_cnti[t * C_ + idx[i]];
        if (cum > k) { med = pht[idx[i]]; break; }
      }
      double A = 0, Bt = 0, inter = 0, sum_p = 0, ex = 0, nfg_t = 0, nfg_all = 0;
#pragma unroll
      for (int c = 1; c < C_; ++c) {
        double cnt_tc = SH_CNT(t, c);
        double mag_tc = SH_MAG(t, c);
        double spred_tc = SH_PRED(t, c);
        if (pht[c] == med) {
          double logit = SH_LRAW(t, c) - BIASD * cnt_tc;
          A += logit - mag_tc;                 // logpc = logit + log1m
          inter += spred_tc;
          nfg_t += cnt_tc;
          nfg_all += s_col[c][0];
          sum_p += s_col[c][1];
          Bt += s_col[c][2] - (-mag_tc);       // sum over t2 != t of log1m
        } else {
          ex += spred_tc;
        }
      }
      double bce  = -(A + Bt + (ntt - nfg_t)*L0 + (N - ntt - (nfg_all - nfg_t))*M0) / N;
      double dice = 1.0 - (2.0*inter + 1.0) / (sum_p + ntt + 1.0);
      s_term[t] = bce + dice + ex / ntt;
    }
  }
  __syncthreads();
  if (threadIdx.x == 0) {
    double res = 0.0;
#pragma unroll
    for (int t = 0; t < TB; ++t) res += s_term[t];
    out[0] = (float)(res / (double)(2 * s_nun + 1));
  }
}

extern "C" void kernel_launch(void* const* d_in, const int* in_sizes, int n_in,
                              void* d_out, int out_size, void* d_ws, size_t ws_size,
                              hipStream_t stream) {
  const float* pred = (const float*)d_in[0];
  const int* tgt = (const int*)d_in[1];
  const int* ntc = (const int*)d_in[2];
  float* out = (float*)d_out;
  char* ws = (char*)d_ws;
  // ws layout (16B-aligned chunks): cls4 | sp | spf | P2 | border | rootcnt | smcnt (~9.5 MB)
  size_t off = 0;
  unsigned* cls4 = (unsigned*)(ws + off);        off += (size_t)NQUAD * 4;          // 4,718,592
  double* sp = (double*)(ws + off);              off += (size_t)SBLK * 160 * 8;     // 2,949,120
  double* spf = (double*)(ws + off);             off += 160 * 8;                    // 1,280
  unsigned* P2 = (unsigned*)(ws + off);          off += (size_t)NNODES * 4;         // 1,179,648
  unsigned short* border = (unsigned short*)(ws + off); off += (size_t)NTILES * 256 * 2; // 589,824
  unsigned* rootcnt = (unsigned*)(ws + off);     off += (size_t)NTILES * 4 * 4;     // 18,432
  unsigned* smcnt = (unsigned*)(ws + off);       off += (size_t)SEAMBLK * 4 * 4;    // 8,448

  hipLaunchKernelGGL(k_stats, dim3(SBLK), dim3(256), 0, stream,
                     (const float4*)pred, (const int4*)tgt, cls4, sp);
  hipLaunchKernelGGL(k_ccl, dim3(NTILES), dim3(256), 0, stream,
                     cls4, border, P2, rootcnt);
  hipLaunchKernelGGL(k_seam, dim3(SEAMBLK), dim3(256), 0, stream,
                     border, P2, smcnt, sp, spf);
  hipLaunchKernelGGL(k_final, dim3(1), dim3(256), 0, stream,
                     spf, rootcnt, smcnt, ntc, out);
}